// Round 4
// baseline (117.274 us; speedup 1.0000x reference)
//
#include <hip/hip_runtime.h>
#include <hip/hip_bf16.h>

// Problem constants (fixed by the reference)
static constexpr int kB = 2;
static constexpr int kNV = 30000;
static constexpr int kD = 8;    // NDIRS
static constexpr int kR = 3;    // NRINGS
static constexpr int kC = 16;   // C
static constexpr int kF = 16;   // NF
static constexpr int NP = (kB * kNV) / 2;   // 30000 vertex-pairs
static constexpr int S  = 3840;             // pair stride == #waves (single-wave blocks)

static constexpr size_t WS_BYTES = (size_t)kB * kNV * kD * kC * 2;  // 15,360,000 (y as bf16)

typedef short short8  __attribute__((ext_vector_type(8)));   // 8 bf16
typedef float floatx4 __attribute__((ext_vector_type(4)));   // MFMA acc

// Per-wave LDS: two buffers of [patch 48x32B | center 16x64B(32 data + 32 zeros)]
static constexpr int CENT_OFS   = 1536;
static constexpr int BUF_STRIDE = 2560;

// Paired f32->bf16 RNE (v_cvt_pk_bf16_f32) — identical rounding everywhere so
// the bf16-workspace path is bit-identical to the fp32-direct path.
__device__ __forceinline__ unsigned pkbf16(float lo, float hi) {
    union { __hip_bfloat162 h; unsigned u; } cv;
    cv.h = __float22bfloat162_rn(make_float2(lo, hi));
    return cv.u;
}

// 8B LDS word from a gathered vector: bf16 path = raw copy, fp32 path = cvt.
__device__ __forceinline__ uint2 to_lds8(const uint2& v) { return v; }
__device__ __forceinline__ uint2 to_lds8(const float4& v) {
    uint2 w; w.x = pkbf16(v.x, v.y); w.y = pkbf16(v.z, v.w); return w;
}

// ---- prepass: y (fp32) -> ws (bf16, same (b,v,d,c) layout, 32B entries) ----
// 7.68M floats; 960000 threads x 8 floats (2x float4 read, 1x uint4 write).
__global__ __launch_bounds__(256) void cvt_kernel(
    const float* __restrict__ y, uint4* __restrict__ o)
{
    const int t = blockIdx.x * 256 + threadIdx.x;            // < 960000
    const float4 a = reinterpret_cast<const float4*>(y)[2 * t];
    const float4 b = reinterpret_cast<const float4*>(y)[2 * t + 1];
    uint4 w;
    w.x = pkbf16(a.x, a.y); w.y = pkbf16(a.z, a.w);
    w.z = pkbf16(b.x, b.y); w.w = pkbf16(b.z, b.w);
    o[t] = w;
}

// Per-pair GEMM: D[16x16] = A[16x416] x B[416x16].
// K map: k = dd*48 + r*16 + c (conv, k<384); k = 384+c (center); 400..415 zero.
//
// WS16=true : gather from the bf16 workspace table — 32B entries, 4 lanes x 8B
//             per entry; halves the random-stream bytes (92->46 MB) and the
//             center read (30.7->15.4 MB); STAGE is a pure copy (no cvt).
// WS16=false: original fp32 direct-gather path (fallback if ws too small).
//
// Depth-2 register->LDS pipeline (depth-3 measured neutral: memory system is
// throughput-saturated, not latency-limited — see round-3 notes).
template <bool WS16>
__global__ __launch_bounds__(64) void sgc_kernel(
    const float* __restrict__ y,          // (B, NV, NDIRS, C) fp32
    const int*   __restrict__ sync_field, // (B, NV, NRINGS, NDIRS, 3)
    const float* __restrict__ kern,       // (R, D, C, F) fp32
    const float* __restrict__ ck,         // (C, F) fp32
    const float* __restrict__ bias,       // (F,)
    const char*  __restrict__ ytab,       // bf16 y table (WS16 only)
    float*       __restrict__ out)        // (B, NV, F)
{
    __shared__ __align__(16) char smem[2 * BUF_STRIDE];

    const int lane = threadIdx.x;        // single wave per block
    const int wid  = blockIdx.x;
    const int f    = lane & 15;          // MFMA col / feature
    const int q    = lane >> 4;          // MFMA k-quad
    const int mvtx = (lane >> 3) & 1;    // A-row vertex-in-pair
    const int md   = lane & 7;           // A-row direction
    const int eSub = lane >> 2;          // entry-in-group (0..15)
    const int iq   = lane & 3;           // sub-chunk within the entry

    using gvec_t = std::conditional_t<WS16, uint2, float4>;  // 8B vs 16B lanes
    constexpr int ESH   = WS16 ? 5 : 6;        // log2(entry bytes)
    constexpr int LSH   = WS16 ? 3 : 4;        // log2(lane chunk bytes)
    constexpr int CENTB = WS16 ? 512 : 1024;   // center bytes per pair
    const char* gb = WS16 ? ytab : reinterpret_cast<const char*>(y);

    // ---- one-time: zero the 32B upper half of all 16 center slots, both bufs
    {
        const int buf = lane >> 5, z = lane & 31;
        const int ofs = buf * BUF_STRIDE + CENT_OFS + (z >> 1) * 64 + 32 + (z & 1) * 16;
        *(uint4*)(smem + ofs) = make_uint4(0u, 0u, 0u, 0u);
    }

    // ---- per-lane chunk geometry + B-fragments (once per wave) ----
    int aOfs[12];
    short8 bfrag[13];
#pragma unroll
    for (int kk = 0; kk < 12; ++kk) {
        const int g   = kk * 4 + q;
        const int dd  = (g * 43) >> 8;       // g/6 for g<48
        const int rem = g - dd * 6;
        const int r   = rem >> 1;
        const int ch  = rem & 1;
        const int rot = (md + dd) & 7;
        aOfs[kk] = ((mvtx * 3 + r) * 8 + rot) * 32 + ch * 16;   // bytes
        const int be = ((r * 8 + dd) * 16 + ch * 8) * 16 + f;
        union { unsigned u[4]; short8 v; } t;
#pragma unroll
        for (int j = 0; j < 4; ++j)
            t.u[j] = pkbf16(kern[be + (2 * j) * 16], kern[be + (2 * j + 1) * 16]);
        bfrag[kk] = t.v;
    }
    {   // center B-chunk: q=0 -> ck c0-7, q=1 -> c8-15, q>=2 -> zeros
        union { unsigned u[4]; short8 v; } t;
        if (q < 2) {
#pragma unroll
            for (int j = 0; j < 4; ++j)
                t.u[j] = pkbf16(ck[(q * 8 + 2 * j) * 16 + f],
                                ck[(q * 8 + 2 * j + 1) * 16 + f]);
        } else {
            t.u[0] = t.u[1] = t.u[2] = t.u[3] = 0u;
        }
        bfrag[12] = t.v;
    }
    const float biasv = bias[f];

    auto cl = [](int v) { return v < NP ? v : NP - 1; };

    // Folded per-lane gather byte offsets for the NEXT patch issue
    // (g=0..2; entry = g*16+eSub).
    int off[3];
    gvec_t A0, A1, A2, Ac, B0, B1, B2, Bc;

#define SF_PRE(cc) do { \
        const int base_ = (cc) * 48; \
        _Pragma("unroll") \
        for (int g_ = 0; g_ < 3; ++g_) { \
            const int* s_ = sync_field + (size_t)(base_ + g_ * 16 + eSub) * 3; \
            off[g_] = (((s_[0] * kNV + s_[1]) * kD + s_[2]) << ESH) + (iq << LSH); \
        } \
    } while (0)

#define ISSUE_G(Rv, cc) do { \
        Rv##0 = *reinterpret_cast<const gvec_t*>(gb + off[0]); \
        Rv##1 = *reinterpret_cast<const gvec_t*>(gb + off[1]); \
        Rv##2 = *reinterpret_cast<const gvec_t*>(gb + off[2]); \
        Rv##c = *reinterpret_cast<const gvec_t*>( \
                    gb + (size_t)(cc) * CENTB + lane * sizeof(gvec_t)); \
    } while (0)

// NOTE: bind Rv##N to locals before member access — `Rv##0.x` is ill-formed
// (the preprocessor lexes `0.x` as one pp-number token, so ## pastes "A0.x").
#define STAGE(Rv, bufbase) do { \
        const gvec_t g0_ = Rv##0, g1_ = Rv##1, g2_ = Rv##2, gc_ = Rv##c; \
        *(uint2*)((bufbase) + 0 * 512 + lane * 8) = to_lds8(g0_); \
        *(uint2*)((bufbase) + 1 * 512 + lane * 8) = to_lds8(g1_); \
        *(uint2*)((bufbase) + 2 * 512 + lane * 8) = to_lds8(g2_); \
        *(uint2*)((bufbase) + CENT_OFS + eSub * 64 + iq * 8) = to_lds8(gc_); \
    } while (0)

#define DRAIN do { \
        __asm__ __volatile__("" ::: "memory"); \
        __builtin_amdgcn_s_waitcnt(0xC07F); /* lgkmcnt(0) only */ \
        __asm__ __volatile__("" ::: "memory"); \
    } while (0)

#define COMPUTE_STORE(bufbase, pp) do { \
        floatx4 acc0 = { biasv, biasv, biasv, biasv }; \
        floatx4 acc1 = { 0.f, 0.f, 0.f, 0.f }; \
        _Pragma("unroll") \
        for (int kk_ = 0; kk_ < 12; kk_ += 2) { \
            const short8 a0_ = *(const short8*)((bufbase) + aOfs[kk_]); \
            const short8 a1_ = *(const short8*)((bufbase) + aOfs[kk_ + 1]); \
            acc0 = __builtin_amdgcn_mfma_f32_16x16x32_bf16(a0_, bfrag[kk_], acc0, 0, 0, 0); \
            acc1 = __builtin_amdgcn_mfma_f32_16x16x32_bf16(a1_, bfrag[kk_ + 1], acc1, 0, 0, 0); \
        } \
        { \
            const short8 ac_ = *(const short8*)((bufbase) + CENT_OFS \
                                                + (lane & 15) * 64 + q * 16); \
            acc0 = __builtin_amdgcn_mfma_f32_16x16x32_bf16(ac_, bfrag[12], acc0, 0, 0, 0); \
        } \
        float mx = fmaxf(fmaxf(acc0[0] + acc1[0], acc0[1] + acc1[1]), \
                         fmaxf(acc0[2] + acc1[2], acc0[3] + acc1[3])); \
        mx = fmaxf(mx, 0.0f); \
        mx = fmaxf(mx, __shfl_xor(mx, 16, 64)); \
        if (((lane >> 4) & 1) == 0) \
            out[(2 * (pp) + (lane >> 5)) * kF + f] = mx; \
    } while (0)

    // ---- prologue: LDS0 <- p; B in flight (p+S); A in flight (p+2S);
    //      off primed for p+3S. Steady-state MLP = 2 gather batches / lane.
    int p = wid;                       // wid < 3840 <= NP
    SF_PRE(p);
    ISSUE_G(A, p);
    SF_PRE(cl(p + S));
    ISSUE_G(B, cl(p + S));
    SF_PRE(cl(p + 2 * S));
    STAGE(A, smem);                    // waits A only; B stays in flight
    ISSUE_G(A, cl(p + 2 * S));
    SF_PRE(cl(p + 3 * S));

    for (;;) {
        // even step: compute buf0 (pair p); stage B (p+S) -> buf1
        STAGE(B, smem + BUF_STRIDE);   // waits B; A stays in flight
        ISSUE_G(B, cl(p + 3 * S));
        SF_PRE(cl(p + 4 * S));
        DRAIN;
        COMPUTE_STORE(smem, p);
        p += S; if (p >= NP) break;

        // odd step: compute buf1 (pair p); stage A (p+S) -> buf0
        STAGE(A, smem);                // waits A; B stays in flight
        ISSUE_G(A, cl(p + 3 * S));
        SF_PRE(cl(p + 4 * S));
        DRAIN;
        COMPUTE_STORE(smem + BUF_STRIDE, p);
        p += S; if (p >= NP) break;
    }

#undef SF_PRE
#undef ISSUE_G
#undef STAGE
#undef DRAIN
#undef COMPUTE_STORE
}

extern "C" void kernel_launch(void* const* d_in, const int* in_sizes, int n_in,
                              void* d_out, int out_size, void* d_ws, size_t ws_size,
                              hipStream_t stream) {
    const float* y    = reinterpret_cast<const float*>(d_in[0]);
    const int*   sf   = reinterpret_cast<const int*>(d_in[1]);
    const float* kern = reinterpret_cast<const float*>(d_in[2]);
    const float* ck   = reinterpret_cast<const float*>(d_in[3]);
    const float* bias = reinterpret_cast<const float*>(d_in[4]);
    float* out = reinterpret_cast<float*>(d_out);

    if (d_ws != nullptr && ws_size >= WS_BYTES) {
        // phase 1: y -> bf16 table in workspace (same RNE rounding as STAGE)
        cvt_kernel<<<3750, 256, 0, stream>>>(y, reinterpret_cast<uint4*>(d_ws));
        // phase 2: main kernel gathers 32B bf16 entries (half the random bytes)
        sgc_kernel<true><<<S, 64, 0, stream>>>(
            y, sf, kern, ck, bias, reinterpret_cast<const char*>(d_ws), out);
    } else {
        // fallback: original fp32 direct-gather path
        sgc_kernel<false><<<S, 64, 0, stream>>>(y, sf, kern, ck, bias, nullptr, out);
    }
}

// Round 5
// 114.280 us; speedup vs baseline: 1.0262x; 1.0262x over previous
//
#include <hip/hip_runtime.h>
#include <hip/hip_bf16.h>

// Problem constants (fixed by the reference)
static constexpr int kB = 2;
static constexpr int kNV = 30000;
static constexpr int kD = 8;    // NDIRS
static constexpr int kR = 3;    // NRINGS
static constexpr int kC = 16;   // C
static constexpr int kF = 16;   // NF
static constexpr int NP = (kB * kNV) / 2;   // 30000 vertex-pairs
static constexpr int S  = 3840;             // pair stride == #waves (single-wave blocks)

typedef short short8  __attribute__((ext_vector_type(8)));   // 8 bf16
typedef float floatx4 __attribute__((ext_vector_type(4)));   // MFMA acc

// Per-wave LDS: two buffers of [patch 48x32B | center 16x64B(32 data + 32 zeros)]
static constexpr int CENT_OFS   = 1536;
static constexpr int BUF_STRIDE = 2560;

// Paired f32->bf16 RNE: compiler emits v_cvt_pk_bf16_f32 (identical rounding
// to the manual round-to-nearest-even bit-twiddle, fewer VALU ops).
__device__ __forceinline__ unsigned pkbf16(float lo, float hi) {
    union { __hip_bfloat162 h; unsigned u; } cv;
    cv.h = __float22bfloat162_rn(make_float2(lo, hi));
    return cv.u;
}

// Per-pair GEMM: D[16x16] = A[16x416] x B[416x16].
// K map: k = dd*48 + r*16 + c (conv, k<384); k = 384+c (center); 400..415 zero.
// Gather: 4 consecutive lanes split one 64B entry (16B each) so the TCP can
// coalesce same-line lane requests within one instruction — 48 64B
// transactions per iteration instead of 192 scattered 16B ones.
//
// Regime (established rounds 2-4): the kernel sits at a random-access
// request-count x miss-latency ceiling (~2.2M line requests ~= 39us).
//   - depth-3 pipeline (more MLP): null  -> miss slots already saturated
//   - bf16 table prepass (half bytes): null -> cost is per-request, not per-byte
//   - __launch_bounds__(64,4): allocator pinned 64 VGPR, spilled pipeline, -44%
// So: depth-2, S=3840, plain launch bounds, fp32 direct gather.
__global__ __launch_bounds__(64) void sgc_kernel(
    const float* __restrict__ y,          // (B, NV, NDIRS, C) fp32
    const int*   __restrict__ sync_field, // (B, NV, NRINGS, NDIRS, 3)
    const float* __restrict__ kern,       // (R, D, C, F) fp32
    const float* __restrict__ ck,         // (C, F) fp32
    const float* __restrict__ bias,       // (F,)
    float*       __restrict__ out)        // (B, NV, F)
{
    __shared__ __align__(16) char smem[2 * BUF_STRIDE];

    const int lane = threadIdx.x;        // single wave per block
    const int wid  = blockIdx.x;
    const int f    = lane & 15;          // MFMA col / feature
    const int q    = lane >> 4;          // MFMA k-quad
    const int mvtx = (lane >> 3) & 1;    // A-row vertex-in-pair
    const int md   = lane & 7;           // A-row direction
    const int eSub = lane >> 2;          // entry-in-group (0..15)
    const int iq   = lane & 3;           // 16B quad within the 64B entry

    // ---- one-time: zero the 32B upper half of all 16 center slots, both bufs
    {
        const int buf = lane >> 5, z = lane & 31;
        const int ofs = buf * BUF_STRIDE + CENT_OFS + (z >> 1) * 64 + 32 + (z & 1) * 16;
        *(uint4*)(smem + ofs) = make_uint4(0u, 0u, 0u, 0u);
    }

    // ---- per-lane chunk geometry + B-fragments (once per wave) ----
    int aOfs[12];
    short8 bfrag[13];
#pragma unroll
    for (int kk = 0; kk < 12; ++kk) {
        const int g   = kk * 4 + q;
        const int dd  = (g * 43) >> 8;       // g/6 for g<48
        const int rem = g - dd * 6;
        const int r   = rem >> 1;
        const int ch  = rem & 1;
        const int rot = (md + dd) & 7;
        aOfs[kk] = ((mvtx * 3 + r) * 8 + rot) * 32 + ch * 16;   // bytes
        const int be = ((r * 8 + dd) * 16 + ch * 8) * 16 + f;
        union { unsigned u[4]; short8 v; } t;
#pragma unroll
        for (int j = 0; j < 4; ++j)
            t.u[j] = pkbf16(kern[be + (2 * j) * 16], kern[be + (2 * j + 1) * 16]);
        bfrag[kk] = t.v;
    }
    {   // center B-chunk: q=0 -> ck c0-7, q=1 -> c8-15, q>=2 -> zeros
        union { unsigned u[4]; short8 v; } t;
        if (q < 2) {
#pragma unroll
            for (int j = 0; j < 4; ++j)
                t.u[j] = pkbf16(ck[(q * 8 + 2 * j) * 16 + f],
                                ck[(q * 8 + 2 * j + 1) * 16 + f]);
        } else {
            t.u[0] = t.u[1] = t.u[2] = t.u[3] = 0u;
        }
        bfrag[12] = t.v;
    }
    const float biasv = bias[f];

    auto cl = [](int v) { return v < NP ? v : NP - 1; };

    // sf-derived per-lane gather byte offsets for the NEXT patch issue
    // (per group g=0..2; entry = g*16+eSub)
    int off[3];
    float4 A0, A1, A2, Ac, B0, B1, B2, Bc;

#define SF_PRE(cc) do { \
        const int base_ = (cc) * 48; \
        _Pragma("unroll") \
        for (int g_ = 0; g_ < 3; ++g_) { \
            const int* s_ = sync_field + (size_t)(base_ + g_ * 16 + eSub) * 3; \
            off[g_] = ((s_[0] * kNV + s_[1]) * kD + s_[2]) * 64 + iq * 16; \
        } \
    } while (0)

#define ISSUE_G(Rv, cc) do { \
        Rv##0 = *reinterpret_cast<const float4*>( \
                    reinterpret_cast<const char*>(y) + off[0]); \
        Rv##1 = *reinterpret_cast<const float4*>( \
                    reinterpret_cast<const char*>(y) + off[1]); \
        Rv##2 = *reinterpret_cast<const float4*>( \
                    reinterpret_cast<const char*>(y) + off[2]); \
        Rv##c = reinterpret_cast<const float4*>(y + (size_t)(cc) * 256)[lane]; \
    } while (0)

// NOTE: bind Rv##N to locals before member access — `Rv##0.x` is ill-formed
// (the preprocessor lexes `0.x` as one pp-number token, so ## pastes "A0.x").
#define STAGE(Rv, bufbase) do { \
        const float4 g0_ = Rv##0, g1_ = Rv##1, g2_ = Rv##2, gc_ = Rv##c; \
        uint2 w_; \
        w_.x = pkbf16(g0_.x, g0_.y); w_.y = pkbf16(g0_.z, g0_.w); \
        *(uint2*)((bufbase) + 0 * 512 + lane * 8) = w_; \
        w_.x = pkbf16(g1_.x, g1_.y); w_.y = pkbf16(g1_.z, g1_.w); \
        *(uint2*)((bufbase) + 1 * 512 + lane * 8) = w_; \
        w_.x = pkbf16(g2_.x, g2_.y); w_.y = pkbf16(g2_.z, g2_.w); \
        *(uint2*)((bufbase) + 2 * 512 + lane * 8) = w_; \
        w_.x = pkbf16(gc_.x, gc_.y); w_.y = pkbf16(gc_.z, gc_.w); \
        *(uint2*)((bufbase) + CENT_OFS + eSub * 64 + iq * 8) = w_; \
    } while (0)

#define DRAIN do { \
        __asm__ __volatile__("" ::: "memory"); \
        __builtin_amdgcn_s_waitcnt(0xC07F); /* lgkmcnt(0) only */ \
        __asm__ __volatile__("" ::: "memory"); \
    } while (0)

#define COMPUTE_STORE(bufbase, pp) do { \
        floatx4 acc0 = { biasv, biasv, biasv, biasv }; \
        floatx4 acc1 = { 0.f, 0.f, 0.f, 0.f }; \
        _Pragma("unroll") \
        for (int kk_ = 0; kk_ < 12; kk_ += 2) { \
            const short8 a0_ = *(const short8*)((bufbase) + aOfs[kk_]); \
            const short8 a1_ = *(const short8*)((bufbase) + aOfs[kk_ + 1]); \
            acc0 = __builtin_amdgcn_mfma_f32_16x16x32_bf16(a0_, bfrag[kk_], acc0, 0, 0, 0); \
            acc1 = __builtin_amdgcn_mfma_f32_16x16x32_bf16(a1_, bfrag[kk_ + 1], acc1, 0, 0, 0); \
        } \
        { \
            const short8 ac_ = *(const short8*)((bufbase) + CENT_OFS \
                                                + (lane & 15) * 64 + q * 16); \
            acc0 = __builtin_amdgcn_mfma_f32_16x16x32_bf16(ac_, bfrag[12], acc0, 0, 0, 0); \
        } \
        float mx = fmaxf(fmaxf(acc0[0] + acc1[0], acc0[1] + acc1[1]), \
                         fmaxf(acc0[2] + acc1[2], acc0[3] + acc1[3])); \
        mx = fmaxf(mx, 0.0f); \
        mx = fmaxf(mx, __shfl_xor(mx, 16, 64)); \
        if (((lane >> 4) & 1) == 0) \
            out[(2 * (pp) + (lane >> 5)) * kF + f] = mx; \
    } while (0)

    // ---- prologue: LDS0 <- p; B in flight (p+S); A in flight (p+2S);
    //      off primed for p+3S. Steady-state MLP = 2 gather batches / lane.
    int p = wid;                       // wid < 3840 <= NP
    SF_PRE(p);
    ISSUE_G(A, p);
    SF_PRE(cl(p + S));
    ISSUE_G(B, cl(p + S));
    SF_PRE(cl(p + 2 * S));
    STAGE(A, smem);                    // waits A only; B stays in flight
    ISSUE_G(A, cl(p + 2 * S));
    SF_PRE(cl(p + 3 * S));

    for (;;) {
        // even step: compute buf0 (pair p); stage B (p+S) -> buf1
        STAGE(B, smem + BUF_STRIDE);   // waits B; A stays in flight
        ISSUE_G(B, cl(p + 3 * S));
        SF_PRE(cl(p + 4 * S));
        DRAIN;
        COMPUTE_STORE(smem, p);
        p += S; if (p >= NP) break;

        // odd step: compute buf1 (pair p); stage A (p+S) -> buf0
        STAGE(A, smem);                // waits A; B stays in flight
        ISSUE_G(A, cl(p + 3 * S));
        SF_PRE(cl(p + 4 * S));
        DRAIN;
        COMPUTE_STORE(smem + BUF_STRIDE, p);
        p += S; if (p >= NP) break;
    }

#undef SF_PRE
#undef ISSUE_G
#undef STAGE
#undef DRAIN
#undef COMPUTE_STORE
}

extern "C" void kernel_launch(void* const* d_in, const int* in_sizes, int n_in,
                              void* d_out, int out_size, void* d_ws, size_t ws_size,
                              hipStream_t stream) {
    const float* y    = reinterpret_cast<const float*>(d_in[0]);
    const int*   sf   = reinterpret_cast<const int*>(d_in[1]);
    const float* kern = reinterpret_cast<const float*>(d_in[2]);
    const float* ck   = reinterpret_cast<const float*>(d_in[3]);
    const float* bias = reinterpret_cast<const float*>(d_in[4]);
    float* out = reinterpret_cast<float*>(d_out);

    sgc_kernel<<<S, 64, 0, stream>>>(y, sf, kern, ck, bias, out);
}